// Round 2
// 157.256 us; speedup vs baseline: 1.0364x; 1.0364x over previous
//
#include <hip/hip_runtime.h>
#include <stdint.h>

#define SEQ 64
#define D 28
#define EMB 784   // 28*28
#define NW 4      // waves per block (one block = one sentence)
#define CH 16     // per-wave chain length: 4 waves x 16 words = 64
#define BUFF 832  // B-buffer floats: 3328 B = exact DMA coverage (3*1024+256)
#define CTW 36    // CT row stride floats (16B-aligned b128 reads, 2-way-free banks)
#define CTSZ (32 * CTW)  // 1152 floats per wave

typedef float float4v __attribute__((ext_vector_type(4)));
typedef __bf16 bf16x8 __attribute__((ext_vector_type(8)));

union FragU { unsigned u[4]; bf16x8 v; };

__device__ __forceinline__ unsigned fbits(float x) { union { float f; unsigned u; } t; t.f = x; return t.u; }
__device__ __forceinline__ float fof(unsigned u) { union { unsigned u; float f; } t; t.u = u; return t.f; }

// Split 8 fp32 (k-order) into hi/lo bf16 fragments (truncation split:
// x = hi + lo + O(2^-16 |x|); MFMA computes hi*hi + hi*lo + lo*hi).
__device__ __forceinline__ void split_frags(const float x[8], bf16x8& hi, bf16x8& lo)
{
    FragU H, L;
#pragma unroll
    for (int p = 0; p < 4; ++p) {
        unsigned ua = fbits(x[2 * p]), ub = fbits(x[2 * p + 1]);
        H.u[p] = (ua >> 16) | (ub & 0xFFFF0000u);
        unsigned la = fbits(x[2 * p]     - fof(ua & 0xFFFF0000u));
        unsigned lb = fbits(x[2 * p + 1] - fof(ub & 0xFFFF0000u));
        L.u[p] = (la >> 16) | (lb & 0xFFFF0000u);
    }
    hi = H.v; lo = L.v;
}

// ---- async global->LDS DMA of one 3136 B row (+192 B tail overread, which
// stays within page-granular allocation slack and lands in LDS bytes
// [3136,3328) of the 3328 B buffer — never read as data).
__device__ __forceinline__ void dma_row(const float* grow, float* lbuf, int lane)
{
    const char* g16 = (const char*)grow + lane * 16;
    const char* g4  = (const char*)grow + 3072 + lane * 4;
    char* l = (char*)lbuf;
    __builtin_amdgcn_global_load_lds((const __attribute__((address_space(1))) void*)(g16),
                                     (__attribute__((address_space(3))) void*)(l), 16, 0, 0);
    __builtin_amdgcn_global_load_lds((const __attribute__((address_space(1))) void*)(g16 + 1024),
                                     (__attribute__((address_space(3))) void*)(l + 1024), 16, 0, 0);
    __builtin_amdgcn_global_load_lds((const __attribute__((address_space(1))) void*)(g16 + 2048),
                                     (__attribute__((address_space(3))) void*)(l + 2048), 16, 0, 0);
    __builtin_amdgcn_global_load_lds((const __attribute__((address_space(1))) void*)(g4),
                                     (__attribute__((address_space(3))) void*)(l + 3072), 4, 0, 0);
}

// ---- fragment helpers (shared by chain and in-block combine) ----

// Publish C (2x2 16x16 D-frags; C/D layout col=lane&15, row=(lane>>4)*4+reg)
// row-major into a stride-36 LDS tile. Banks: 2-way aliasing only -> free.
__device__ __forceinline__ void publish_C(const float4v acc[2][2], float* dst, int lane)
{
    const int c = lane & 15;
    const int quad = lane >> 4;
#pragma unroll
    for (int R = 0; R < 2; ++R)
#pragma unroll
        for (int Cc = 0; Cc < 2; ++Cc)
#pragma unroll
            for (int i = 0; i < 4; ++i)
                dst[(16 * R + 4 * quad + i) * CTW + 16 * Cc + c] = acc[R][Cc][i];
}

// A-frags from a stride-36 tile: lane m=16R+c, k=8*quad+j'; k>=28 zeroed.
__device__ __forceinline__ void load_A(const float* ct, int lane, bf16x8 Ah[2], bf16x8 Al[2])
{
    const int c = lane & 15;
    const int quad = lane >> 4;
    const bool q3 = (quad == 3);
#pragma unroll
    for (int R = 0; R < 2; ++R) {
        const float* ap = ct + (16 * R + c) * CTW + 8 * quad;
        float4v x0 = *(const float4v*)ap;
        float4v x1 = *(const float4v*)(ap + 4);
        if (q3) x1 = float4v{0.f, 0.f, 0.f, 0.f};  // k=28..31 -> 0
        float x[8] = {x0.x, x0.y, x0.z, x0.w, x1.x, x1.y, x1.z, x1.w};
        split_frags(x, Ah[R], Al[R]);
    }
}

// B-frags from a row-major fp32 tile with runtime stride (28 for DMA'd table
// rows, 36 for CT partials): lane n=16Cc+c, k=8*quad+t; k>=28 zeroed.
__device__ __forceinline__ void load_B(const float* buf, int stride, int lane, bf16x8 Bh[2], bf16x8 Bl[2])
{
    const int c = lane & 15;
    const int quad = lane >> 4;
    const bool q3 = (quad == 3);
#pragma unroll
    for (int Cc = 0; Cc < 2; ++Cc) {
        const float* bp = buf + (8 * quad) * stride + 16 * Cc + c;
        float x[8];
#pragma unroll
        for (int t = 0; t < 8; ++t) x[t] = bp[t * stride];
        if (q3) { x[4] = 0.f; x[5] = 0.f; x[6] = 0.f; x[7] = 0.f; }
        split_frags(x, Bh[Cc], Bl[Cc]);
    }
}

// C_new = C * M  (hi*hi + hi*lo + lo*hi)
__device__ __forceinline__ void mm_step(float4v acc[2][2], const bf16x8 Ah[2], const bf16x8 Al[2],
                                        const bf16x8 Bh[2], const bf16x8 Bl[2])
{
#pragma unroll
    for (int R = 0; R < 2; ++R)
#pragma unroll
        for (int Cc = 0; Cc < 2; ++Cc) {
            float4v d = {0.f, 0.f, 0.f, 0.f};
            d = __builtin_amdgcn_mfma_f32_16x16x32_bf16(Ah[R], Bh[Cc], d, 0, 0, 0);
            d = __builtin_amdgcn_mfma_f32_16x16x32_bf16(Ah[R], Bl[Cc], d, 0, 0, 0);
            d = __builtin_amdgcn_mfma_f32_16x16x32_bf16(Al[R], Bh[Cc], d, 0, 0, 0);
            acc[R][Cc] = d;
        }
}

// ================= shared MFMA chain engine =================
// acc = M_{row 0}; then acc <- acc * M_{rowptr(j)} for j=1..CNT-1.
// Per step: publish C to CT (stride 36), A-frags from CT (b128), B-frags from
// the DMA'd fp32 row (strided b32), 12 MFMAs (hi/lo split). k>=28 zeroed in
// registers; pad rows/cols only ever flow to pad rows/cols.
template <int CNT, typename F>
__device__ __forceinline__ void mfma_chain(F rowptr,
                                           float* __restrict__ CTw,
                                           float* __restrict__ B0,
                                           float* __restrict__ B1,
                                           float4v acc[2][2],
                                           int lane)
{
    const int c = lane & 15;
    const int quad = lane >> 4;

    dma_row(rowptr(0), B0, lane);
    dma_row(rowptr(1), B1, lane);
    __builtin_amdgcn_s_waitcnt(0x0074);  // vmcnt(4): row0 landed, row1 in flight

    // init: acc = M0 element-wise from B0. Clamped indices keep reads inside
    // the 832-float buffer; pad rows/cols duplicate row/col 27 (flows to pad).
#pragma unroll
    for (int R = 0; R < 2; ++R)
#pragma unroll
        for (int Cc = 0; Cc < 2; ++Cc)
#pragma unroll
            for (int i = 0; i < 4; ++i) {
                const int rr = 16 * R + 4 * quad + i;
                const int cc = 16 * Cc + c;
                acc[R][Cc][i] = B0[(rr < D ? rr : D - 1) * D + (cc < D ? cc : D - 1)];
            }
    __builtin_amdgcn_s_waitcnt(0xC07F);  // drain init reads before B0 reuse

#pragma unroll 1
    for (int j = 1; j < CNT; ++j) {
        const int jn = (j + 1 < CNT) ? (j + 1) : j;  // last step re-issues row j
        float* nB = (j & 1) ? B0 : B1;   // buffer for row j+1
        float* cB = (j & 1) ? B1 : B0;   // buffer holding row j
        dma_row(rowptr(jn), nB, lane);   // (final re-issue hits L1/L2, keeps vmcnt uniform)

        publish_C(acc, CTw, lane);

        __builtin_amdgcn_sched_barrier(0);
        __builtin_amdgcn_s_waitcnt(0x0074);  // vmcnt(4) lgkmcnt(0)
        __builtin_amdgcn_sched_barrier(0);

        bf16x8 Ah[2], Al[2], Bh[2], Bl[2];
        load_A(CTw, lane, Ah, Al);
        load_B(cB, D, lane, Bh, Bl);
        mm_step(acc, Ah, Al, Bh, Bl);
    }
}

// Store rows/cols < 28 of the D-frag accumulator to a row-major 784 buffer.
__device__ __forceinline__ void store_acc(const float4v acc[2][2],
                                          float* __restrict__ orow, int lane)
{
    const int c = lane & 15;
    const int quad = lane >> 4;
#pragma unroll
    for (int R = 0; R < 2; ++R)
#pragma unroll
        for (int Cc = 0; Cc < 2; ++Cc)
#pragma unroll
            for (int i = 0; i < 4; ++i) {
                const int row = 16 * R + 4 * quad + i;
                const int col = 16 * Cc + c;
                if (row < D && col < D) orow[row * D + col] = acc[R][Cc][i];
            }
}

// ================= fused kernel: one block per sentence =================
// 4 waves; wave w computes the product of words 16w..16w+15 (15 chain steps),
// publishes its partial into its CT tile, then after one barrier all waves
// redundantly combine the 4 partials (3 matmul steps, scratch = own B-bufs);
// wave 0 stores. No workspace, no second kernel, no inter-kernel drain.
// LDS: 4*(4608 CT + 6656 BB) = 45056 B -> 3 blocks/CU resident (12 waves/CU;
// 12 waves x 2 rows x 3136 B = 75 KB DMA in flight per CU, ~5x what 6.3 TB/s
// requires -> gather MLP is not occupancy-limited).
__global__ __launch_bounds__(NW * 64, 1) void w2m_fused(
    const int* __restrict__ sent,
    const float* __restrict__ table,
    float* __restrict__ out)
{
    __shared__ float SH[NW * CTSZ + NW * 2 * BUFF] __attribute__((aligned(16)));
    const int lane = threadIdx.x & 63;
    const int wid  = threadIdx.x >> 6;   // 0..3
    const int b = blockIdx.x;

    float* CTw = &SH[wid * CTSZ];
    float* B0  = &SH[NW * CTSZ + wid * 2 * BUFF];
    float* B1  = B0 + BUFF;

    const int myidx = sent[b * SEQ + CH * wid + (lane & (CH - 1))];
    int jl[CH];
#pragma unroll
    for (int j = 0; j < CH; ++j) jl[j] = __builtin_amdgcn_readlane(myidx, j);

    float4v acc[2][2];
    mfma_chain<CH>([&](int j) { return table + (size_t)jl[j] * EMB; },
                   CTw, B0, B1, acc, lane);

    // publish this wave's partial P_w into its CT tile.
    publish_C(acc, CTw, lane);
    __syncthreads();  // drains own vmcnt/lgkmcnt per wave; CT[0..3] now stable

    // ---- in-block combine: acc = P0 * P1 * P2 * P3 (redundant on all waves).
    const int c = lane & 15;
    const int quad = lane >> 4;
    // acc = P0, element-wise from CT0 (rows/cols 28..31 hold finite pad dups;
    // they only ever flow to pad rows/cols, masked at store).
#pragma unroll
    for (int R = 0; R < 2; ++R)
#pragma unroll
        for (int Cc = 0; Cc < 2; ++Cc)
#pragma unroll
            for (int i = 0; i < 4; ++i)
                acc[R][Cc][i] = SH[(16 * R + 4 * quad + i) * CTW + 16 * Cc + c];

    float* Sw = B0;  // per-wave scratch: 2*BUFF = 1664 floats >= 32*36 = 1152
#pragma unroll 1
    for (int j = 1; j < NW; ++j) {
        publish_C(acc, Sw, lane);
        // explicit fence for the LDS RAW (publish -> load_A); cheap and
        // removes any reliance on compiler alias tracking (rule #18 spirit).
        __builtin_amdgcn_sched_barrier(0);
        __builtin_amdgcn_s_waitcnt(0xC07F);  // lgkmcnt(0)
        __builtin_amdgcn_sched_barrier(0);
        bf16x8 Ah[2], Al[2], Bh[2], Bl[2];
        load_A(Sw, lane, Ah, Al);
        load_B(&SH[j * CTSZ], CTW, lane, Bh, Bl);
        mm_step(acc, Ah, Al, Bh, Bl);
    }

    if (wid == 0) store_acc(acc, out + (size_t)b * EMB, lane);
}

extern "C" void kernel_launch(void* const* d_in, const int* in_sizes, int n_in,
                              void* d_out, int out_size, void* d_ws, size_t ws_size,
                              hipStream_t stream) {
    const int* sent = (const int*)d_in[0];
    const float* table = (const float*)d_in[1];
    float* out = (float*)d_out;
    const int batch = in_sizes[0] / SEQ;                  // 1024
    (void)d_ws; (void)ws_size;                            // workspace unused

    hipLaunchKernelGGL(w2m_fused, dim3(batch), dim3(NW * 64), 0, stream,
                       sent, table, out);
}